// Round 3
// baseline (934.121 us; speedup 1.0000x reference)
//
#include <hip/hip_runtime.h>

#define NEGV  (-1e30f)
#define LOG2E 1.4426950408889634f
#define LN2   0.6931471805599453f

namespace {
constexpr int B    = 64;
constexpr int T    = 2000;
constexpr int V    = 256;
constexpr int S    = 400;
constexpr int SPL  = 14;          // states per lane (EVEN -> uniform parity; 64*14=896 >= 801)
constexpr int NODD = SPL / 2;     // odd (token) states per lane
constexpr int CH   = 8;           // time rows per staged chunk (CH*V = 64 lanes * 8 float4)
constexpr int NCHT = T / CH;      // 250 chunks available in memory
}

__device__ __forceinline__ float fexp2(float x){ return __builtin_amdgcn_exp2f(x); }
__device__ __forceinline__ float flog2(float x){ return __builtin_amdgcn_logf(x); }

// One WAVE per batch item, wave-synchronous (zero barriers in the hot loop).
// Alpha lives in registers (14 states/lane); the only cross-lane value per
// step is alpha[s0-1] via __shfl_up. logp rows staged in LDS (pre-scaled by
// log2(e)); even/blank states read a broadcast column, odd states do 7
// random gathers. Invalid states (s >= 2*tl+1) are left unmasked: alpha
// dependencies only flow toward higher s, so they never touch the readout.
__global__ __launch_bounds__(64)
void ctc_alpha_kernel(const float* __restrict__ logp,
                      const int* __restrict__ targets,
                      const int* __restrict__ input_len,
                      const int* __restrict__ target_len,
                      float* __restrict__ out)
{
  const int b    = blockIdx.x;
  const int lane = threadIdx.x;
  const float* lp = logp + (size_t)b * T * V;
  const int il = input_len[b];
  const int tl = target_len[b];

  __shared__ float rows[2][CH * V];   // 16 KB, double-buffered
  __shared__ float afin[64 * SPL];    // 3.5 KB, final readout only

  // ---- t-invariant per-lane constants: tokens + additive skip gates ----
  const int* tg = targets + (size_t)b * S;
  int   ev[NODD];
  float sk[NODD];                      // 0 if skip allowed, NEGV otherwise
  const int k0 = NODD * lane;
  #pragma unroll
  for (int j = 0; j < NODD; ++j) {
    int k = k0 + j; if (k > S - 1) k = S - 1;   // clamp: garbage region only
    int e = tg[k];
    ev[j] = e;
    sk[j] = (k == 0 || e != tg[k - 1]) ? 0.0f : NEGV;
  }

  // ---- stage chunk 0 (rows 0..7), scaled to base-2 ----
  #pragma unroll
  for (int k = 0; k < CH; ++k) {
    float4 r = ((const float4*)lp)[lane + 64 * k];
    r.x *= LOG2E; r.y *= LOG2E; r.z *= LOG2E; r.w *= LOG2E;
    ((float4*)&rows[0][0])[lane + 64 * k] = r;
  }
  __syncthreads();   // single wave: just a waitcnt fence, once

  // ---- t = 0 init ----
  float a[SPL];
  #pragma unroll
  for (int j = 0; j < SPL; ++j) a[j] = NEGV;
  {
    float i0 = rows[0][1];
    float i1 = rows[0][ev[0]];
    if (lane == 0) { a[0] = i0; a[1] = i1; }
  }

  // ---- main recursion: t in [1, il) ----
  const int NCHb = (il + CH - 1) / CH;
  for (int c = 0; c < NCHb; ++c) {
    // prefetch next chunk into registers (8 float4/lane)
    float4 pre[CH];
    const bool ok = (c + 1 < NCHT);
    if (ok) {
      const int base = (c + 1) * (CH * V / 4);
      #pragma unroll
      for (int k = 0; k < CH; ++k) pre[k] = ((const float4*)lp)[base + lane + 64 * k];
    }

    const float* rc = &rows[c & 1][0];
    const int iend   = min(CH, il - c * CH);
    const int istart = (c == 0) ? 1 : 0;
    #pragma unroll
    for (int i = 0; i < CH; ++i) {
      if (i >= istart && i < iend) {
        const float* row = rc + i * V;

        float hl = __shfl_up(a[SPL - 1], 1);    // alpha[s0-1] from lane-1
        if (lane == 0) hl = NEGV;
        const float lpb = row[1];               // blank column: broadcast
        float lpt[NODD];
        #pragma unroll
        for (int j = 0; j < NODD; ++j) lpt[j] = row[ev[j]];

        // descending update: state j only reads indices <= j (in-place safe)
        #pragma unroll
        for (int j = SPL - 1; j >= 2; --j) {
          if (j & 1) {            // odd/token: lse3(a[j], a[j-1], skip? a[j-2])
            float z = a[j - 2] + sk[(j - 1) >> 1];
            float m = fmaxf(fmaxf(a[j], a[j - 1]), z);
            float s = fexp2(a[j] - m) + fexp2(a[j - 1] - m) + fexp2(z - m);
            a[j] = m + flog2(s) + lpt[(j - 1) >> 1];
          } else {                // even/blank: lse2(a[j], a[j-1])
            float m = fmaxf(a[j], a[j - 1]);
            float d = a[j] - a[j - 1];
            a[j] = m + flog2(1.0f + fexp2(-fabsf(d))) + lpb;
          }
        }
        { // j = 1: lse3(a[1], a[0], skip? hl)
          float z = hl + sk[0];
          float m = fmaxf(fmaxf(a[1], a[0]), z);
          float s = fexp2(a[1] - m) + fexp2(a[0] - m) + fexp2(z - m);
          a[1] = m + flog2(s) + lpt[0];
        }
        { // j = 0: lse2(a[0], hl)
          float m = fmaxf(a[0], hl);
          float d = a[0] - hl;
          a[0] = m + flog2(1.0f + fexp2(-fabsf(d))) + lpb;
        }
      }
    }

    // commit prefetched chunk (scaled) into the other buffer — same wave,
    // hardware in-order DS + compiler waitcnts give ordering, no barrier.
    if (ok) {
      #pragma unroll
      for (int k = 0; k < CH; ++k) {
        float4 r = pre[k];
        r.x *= LOG2E; r.y *= LOG2E; r.z *= LOG2E; r.w *= LOG2E;
        ((float4*)&rows[(c & 1) ^ 1][0])[lane + 64 * k] = r;
      }
    }
  }

  // ---- readout + fused mean (one atomic per block) ----
  #pragma unroll
  for (int j = 0; j < SPL; ++j) afin[lane * SPL + j] = a[j];
  __syncthreads();
  if (lane == 0) {
    const float ae  = afin[2 * tl];
    const float ae1 = afin[2 * tl - 1];
    const float m   = fmaxf(ae, ae1);
    const float ll  = (m + flog2(fexp2(ae - m) + fexp2(ae1 - m))) * LN2;
    float loss = -ll;
    if (!(loss < 1e29f)) loss = 0.0f;
    atomicAdd(out, loss / ((float)tl * (float)B));
  }
}

__global__ void ctc_zero_kernel(float* __restrict__ out) { out[0] = 0.0f; }

extern "C" void kernel_launch(void* const* d_in, const int* in_sizes, int n_in,
                              void* d_out, int out_size, void* d_ws, size_t ws_size,
                              hipStream_t stream) {
  const float* logp    = (const float*)d_in[0];
  const int*   targets = (const int*)d_in[1];
  const int*   il      = (const int*)d_in[2];
  const int*   tl      = (const int*)d_in[3];
  float* out = (float*)d_out;

  ctc_zero_kernel<<<1, 1, 0, stream>>>(out);
  ctc_alpha_kernel<<<B, 64, 0, stream>>>(logp, targets, il, tl, out);
}

// Round 4
// 572.409 us; speedup vs baseline: 1.6319x; 1.6319x over previous
//
#include <hip/hip_runtime.h>

#define NEGV  (-1e30f)
#define LOG2E 1.4426950408889634f
#define LN2   0.6931471805599453f

namespace {
constexpr int B   = 64;
constexpr int T   = 2000;
constexpr int V   = 256;
constexpr int S   = 400;
constexpr int NW  = 4;                         // pipeline waves per chain
constexpr int CHK = 8;                         // steps per handoff chunk
constexpr int NCT = (T - 1 + CHK - 1) / CHK;   // 250 chunks max
}

__device__ __forceinline__ float fexp2(float x){ return __builtin_amdgcn_exp2f(x); }
__device__ __forceinline__ float flog2(float x){ return __builtin_amdgcn_logf(x); }

// One block (4 waves) per batch item. Wave w owns states [256w, 256w+256),
// 4 states/lane, alpha in registers. Dependencies flow only upward in s, so
// wave w+1 lags wave w by one 8-step chunk and consumes a 1-float/step
// boundary stream via LDS (acquire/release counter — NO s_barrier in the
// loop; wave 0 never waits => no deadlock). logp token columns are gathered
// straight from global with a chunk of register prefetch (leader warms L1
// for the laggards). Invalid states (s >= 2*tl+1) are left unmasked: info
// only flows upward, the readout at 2*tl never sees them.
__global__ __launch_bounds__(NW * 64)
void ctc_alpha_kernel(const float* __restrict__ logp,
                      const int* __restrict__ targets,
                      const int* __restrict__ input_len,
                      const int* __restrict__ target_len,
                      float* __restrict__ out)
{
  const int b    = blockIdx.x;
  const int tid  = threadIdx.x;
  const int w    = tid >> 6;
  const int lane = tid & 63;
  const float* __restrict__ lp = logp + (size_t)b * T * V;
  const int il = input_len[b];
  const int tl = target_len[b];

  __shared__ float bnd[NW - 1][T + CHK];   // boundary stream per interface
  __shared__ int   cnt[NW - 1];            // chunks completed by producer
  __shared__ float afin[NW * 64 * 4];      // final alpha readout

  if (tid < NW - 1) { cnt[tid] = 0; bnd[tid][0] = NEGV; }

  // ---- t-invariant per-lane constants ----
  const int* tg = targets + (size_t)b * S;
  const int s0 = (w << 8) + (lane << 2);       // first owned state (even)
  int k1 = s0 >> 1;       if (k1 > S - 1) k1 = S - 1;   // token for s0+1
  int k3 = (s0 >> 1) + 1; if (k3 > S - 1) k3 = S - 1;   // token for s0+3
  const int e1 = tg[k1];
  const int e3 = tg[k3];
  const float sk1 = (k1 == 0 || e1 != tg[k1 - 1]) ? 0.0f : NEGV;
  const float sk3 = (e3 != tg[k3 - 1]) ? 0.0f : NEGV;   // k3 >= 1 always

  __syncthreads();   // once: cnt/bnd[0] visible to all waves

  // ---- t = 0 init (base-2 domain) ----
  float a0 = NEGV, a1 = NEGV, a2 = NEGV, a3 = NEGV;
  if (w == 0 && lane == 0) {
    a0 = lp[1]  * LOG2E;
    a1 = lp[e1] * LOG2E;
  }

  // ---- preload gather chunk 0 (t = 1..8) ----
  float cb[CHK], c1[CHK], c3[CHK];
  #pragma unroll
  for (int i = 0; i < CHK; ++i) {
    const float* rowp = lp + (size_t)(1 + i) * V;
    cb[i] = rowp[1]; c1[i] = rowp[e1]; c3[i] = rowp[e3];
  }

  const int NCH = (il - 1 + CHK - 1) / CHK;
  for (int c = 0; c < NCH; ++c) {
    const int t0 = 1 + c * CHK;

    // prefetch next chunk's gathers (overlaps spin + this chunk's compute)
    float nb[CHK], n1[CHK], n3[CHK];
    if (c + 1 < NCT) {
      #pragma unroll
      for (int i = 0; i < CHK; ++i) {
        int tt = t0 + CHK + i; if (tt > T - 1) tt = T - 1;   // clamp: tail
        const float* rowp = lp + (size_t)tt * V;
        nb[i] = rowp[1]; n1[i] = rowp[e1]; n3[i] = rowp[e3];
      }
    }

    // boundary values bnd[t-1] for t in this chunk (broadcast reads)
    float bq[CHK];
    if (w > 0) {
      while (__hip_atomic_load(&cnt[w - 1], __ATOMIC_ACQUIRE,
                               __HIP_MEMORY_SCOPE_WORKGROUP) < c + 1)
        __builtin_amdgcn_s_sleep(2);
      const float4 q0 = *(const float4*)&bnd[w - 1][c * CHK];
      const float4 q1 = *(const float4*)&bnd[w - 1][c * CHK + 4];
      bq[0]=q0.x; bq[1]=q0.y; bq[2]=q0.z; bq[3]=q0.w;
      bq[4]=q1.x; bq[5]=q1.y; bq[6]=q1.z; bq[7]=q1.w;
    } else {
      #pragma unroll
      for (int i = 0; i < CHK; ++i) bq[i] = NEGV;
    }

    float pb[CHK];
    #pragma unroll
    for (int i = 0; i < CHK; ++i) {
      const int t = t0 + i;
      if (t < il) {                       // uniform branch per wave
        float hl = __shfl_up(a3, 1);      // alpha[s0-1] from lane-1
        if (lane == 0) hl = bq[i];        // ...or from producer wave
        const float lpb = cb[i] * LOG2E;
        const float lp1 = c1[i] * LOG2E;
        const float lp3 = c3[i] * LOG2E;
        // descending in-place: each state reads only OLD lower values
        { // s0+3 (odd): lse3(a3, a2, sk3? a1)
          float z = a1 + sk3;
          float m = fmaxf(fmaxf(a3, a2), z);
          a3 = m + flog2(fexp2(a3 - m) + fexp2(a2 - m) + fexp2(z - m)) + lp3;
        }
        { // s0+2 (even): lse2(a2, a1)
          float m = fmaxf(a2, a1);
          float d = a2 - a1;
          a2 = m + flog2(1.0f + fexp2(-fabsf(d))) + lpb;
        }
        { // s0+1 (odd): lse3(a1, a0, sk1? hl)
          float z = hl + sk1;
          float m = fmaxf(fmaxf(a1, a0), z);
          a1 = m + flog2(fexp2(a1 - m) + fexp2(a0 - m) + fexp2(z - m)) + lp1;
        }
        { // s0 (even): lse2(a0, hl)
          float m = fmaxf(a0, hl);
          float d = a0 - hl;
          a0 = m + flog2(1.0f + fexp2(-fabsf(d))) + lpb;
        }
      }
      pb[i] = a3;
    }

    // publish boundary stream + release counter (single lane, in-order DS)
    if (w < NW - 1 && lane == 63) {
      #pragma unroll
      for (int i = 0; i < CHK; ++i) bnd[w][t0 + i] = pb[i];
      __hip_atomic_store(&cnt[w], c + 1, __ATOMIC_RELEASE,
                         __HIP_MEMORY_SCOPE_WORKGROUP);
    }

    #pragma unroll
    for (int i = 0; i < CHK; ++i) { cb[i] = nb[i]; c1[i] = n1[i]; c3[i] = n3[i]; }
  }

  // ---- readout + fused mean ----
  afin[s0 + 0] = a0; afin[s0 + 1] = a1;
  afin[s0 + 2] = a2; afin[s0 + 3] = a3;
  __syncthreads();
  if (tid == 0) {
    const float ae  = afin[2 * tl];
    const float ae1 = afin[2 * tl - 1];
    const float m   = fmaxf(ae, ae1);
    const float ll  = (m + flog2(fexp2(ae - m) + fexp2(ae1 - m))) * LN2;
    float loss = -ll;
    if (!(loss < 1e29f)) loss = 0.0f;
    atomicAdd(out, loss / ((float)tl * (float)B));
  }
}

__global__ void ctc_zero_kernel(float* __restrict__ out) { out[0] = 0.0f; }

extern "C" void kernel_launch(void* const* d_in, const int* in_sizes, int n_in,
                              void* d_out, int out_size, void* d_ws, size_t ws_size,
                              hipStream_t stream) {
  const float* logp    = (const float*)d_in[0];
  const int*   targets = (const int*)d_in[1];
  const int*   il      = (const int*)d_in[2];
  const int*   tl      = (const int*)d_in[3];
  float* out = (float*)d_out;

  ctc_zero_kernel<<<1, 1, 0, stream>>>(out);
  ctc_alpha_kernel<<<B, NW * 64, 0, stream>>>(logp, targets, il, tl, out);
}

// Round 5
// 505.328 us; speedup vs baseline: 1.8485x; 1.1327x over previous
//
#include <hip/hip_runtime.h>

#define NEGV  (-1e30f)
#define LOG2E 1.4426950408889634f
#define LN2   0.6931471805599453f

namespace {
constexpr int B   = 64;
constexpr int T   = 2000;
constexpr int V   = 256;
constexpr int S   = 400;
constexpr int NW  = 8;                         // pipeline waves per chain
constexpr int CHK = 8;                         // steps per handoff chunk
constexpr int NCT = (T - 1 + CHK - 1) / CHK;   // chunks available in memory
}

__device__ __forceinline__ float fexp2(float x){ return __builtin_amdgcn_exp2f(x); }
__device__ __forceinline__ float flog2(float x){ return __builtin_amdgcn_logf(x); }

// whole-wave shift right by 1 lane (lane i gets lane i-1; lane 0 -> 0.0f).
// VALU DPP op (~2 cyc) instead of ds_bpermute (~120 cyc).
__device__ __forceinline__ float wave_shr1(float x) {
  int v = __builtin_amdgcn_update_dpp(0, __builtin_bit_cast(int, x),
                                      0x138 /*WAVE_SHR1*/, 0xf, 0xf, true);
  return __builtin_bit_cast(float, v);
}

// One block (8 waves) per batch item. Lane owns states {2*tid, 2*tid+1}
// (even=blank, odd=token), alpha in registers. Dependencies flow only
// upward in s: wave w+1 lags wave w by one 8-step chunk, consuming a
// 1-float/step boundary stream via LDS with an acquire/release counter —
// no s_barrier in the loop, wave 0 never waits (no deadlock). In-wave halo
// alpha[s0-1] comes via DPP wave_shr:1. Token log-probs are gathered from
// global with one chunk of register prefetch (lead wave warms L1/L2 for
// the laggards). States >= 2*tl+1 are left unmasked: info only flows
// upward, the readout at 2*tl never sees them.
__global__ __launch_bounds__(NW * 64)
void ctc_alpha_kernel(const float* __restrict__ logp,
                      const int* __restrict__ targets,
                      const int* __restrict__ input_len,
                      const int* __restrict__ target_len,
                      float* __restrict__ out)
{
  const int b    = blockIdx.x;
  const int tid  = threadIdx.x;
  const int w    = tid >> 6;
  const int lane = tid & 63;
  const bool lane0 = (lane == 0);
  const float* __restrict__ lp = logp + (size_t)b * T * V;
  const int il = input_len[b];
  const int tl = target_len[b];

  __shared__ float bnd[NW - 1][T + CHK];   // boundary stream per interface
  __shared__ int   cnt[NW - 1];            // chunks completed by producer
  __shared__ float afin[NW * 64 * 2];      // final alpha readout

  if (tid < NW - 1) { cnt[tid] = 0; bnd[tid][0] = NEGV; }

  // ---- t-invariant per-lane constants: token for state 2*tid+1 ----
  const int* tg = targets + (size_t)b * S;
  const int k1 = (tid < S) ? tid : (S - 1);     // clamp: garbage region only
  const int e1 = tg[k1];
  const float sk1 = (k1 == 0 || e1 != tg[k1 - 1]) ? 0.0f : NEGV;

  __syncthreads();   // cnt/bnd[0] visible to all waves

  // ---- t = 0 init (base-2 log domain) ----
  float a0 = NEGV, a1 = NEGV;
  if (tid == 0) {
    a0 = lp[1]  * LOG2E;
    a1 = lp[e1] * LOG2E;
  }

  // ---- preload gather chunk 0 (t = 1..CHK), pre-scaled ----
  float cb[CHK], c1[CHK];
  #pragma unroll
  for (int i = 0; i < CHK; ++i) {
    const float* rowp = lp + (size_t)(1 + i) * V;
    cb[i] = rowp[1]  * LOG2E;
    c1[i] = rowp[e1] * LOG2E;
  }

  const int NCH = (il - 1 + CHK - 1) / CHK;
  for (int c = 0; c < NCH; ++c) {
    const int t0 = 1 + c * CHK;

    // prefetch next chunk's gathers (overlap with this chunk's compute)
    float nb[CHK], n1[CHK];
    const bool pf = (c + 1 < NCT);
    if (pf) {
      #pragma unroll
      for (int i = 0; i < CHK; ++i) {
        int tt = t0 + CHK + i; if (tt > T - 1) tt = T - 1;   // tail clamp
        const float* rowp = lp + (size_t)tt * V;
        nb[i] = rowp[1]; n1[i] = rowp[e1];
      }
    }

    // boundary values bnd[t-1] for this chunk (broadcast reads)
    float bq[CHK];
    if (w > 0) {
      while (__hip_atomic_load(&cnt[w - 1], __ATOMIC_ACQUIRE,
                               __HIP_MEMORY_SCOPE_WORKGROUP) < c + 1)
        __builtin_amdgcn_s_sleep(2);
      const float4 q0 = *(const float4*)&bnd[w - 1][c * CHK];
      const float4 q1 = *(const float4*)&bnd[w - 1][c * CHK + 4];
      bq[0]=q0.x; bq[1]=q0.y; bq[2]=q0.z; bq[3]=q0.w;
      bq[4]=q1.x; bq[5]=q1.y; bq[6]=q1.z; bq[7]=q1.w;
    } else {
      #pragma unroll
      for (int i = 0; i < CHK; ++i) bq[i] = NEGV;
    }

    float pb[CHK];
    #pragma unroll
    for (int i = 0; i < CHK; ++i) {
      const int t = t0 + i;
      if (t < il) {                           // wave-uniform branch
        float hl = wave_shr1(a1);             // alpha[s0-1] from lane-1
        hl = lane0 ? bq[i] : hl;              // ...or from producer wave
        // odd/token state: lse3(a1, a0, sk1? hl) + lp[token]
        float z  = hl + sk1;
        float m1 = fmaxf(fmaxf(a1, a0), z);
        float s1 = fexp2(a1 - m1) + fexp2(a0 - m1) + fexp2(z - m1);
        float v1 = m1 + flog2(s1) + c1[i];
        // even/blank state: lse2(a0, hl) + lp[blank]
        float m0 = fmaxf(a0, hl);
        float d0 = a0 - hl;
        float v0 = m0 + flog2(1.0f + fexp2(-fabsf(d0))) + cb[i];
        a1 = v1; a0 = v0;
      }
      pb[i] = a1;
    }

    // publish boundary stream + release counter (single lane, in-order DS)
    if (w < NW - 1 && lane == 63) {
      #pragma unroll
      for (int i = 0; i < CHK; ++i) bnd[w][t0 + i] = pb[i];
      __hip_atomic_store(&cnt[w], c + 1, __ATOMIC_RELEASE,
                         __HIP_MEMORY_SCOPE_WORKGROUP);
    }

    #pragma unroll
    for (int i = 0; i < CHK; ++i) { cb[i] = nb[i] * LOG2E; c1[i] = n1[i] * LOG2E; }
  }

  // ---- readout + fused mean ----
  afin[2 * tid]     = a0;
  afin[2 * tid + 1] = a1;
  __syncthreads();
  if (tid == 0) {
    const float ae  = afin[2 * tl];
    const float ae1 = afin[2 * tl - 1];
    const float m   = fmaxf(ae, ae1);
    const float ll  = (m + flog2(fexp2(ae - m) + fexp2(ae1 - m))) * LN2;
    float loss = -ll;
    if (!(loss < 1e29f)) loss = 0.0f;
    atomicAdd(out, loss / ((float)tl * (float)B));
  }
}

__global__ void ctc_zero_kernel(float* __restrict__ out) { out[0] = 0.0f; }

extern "C" void kernel_launch(void* const* d_in, const int* in_sizes, int n_in,
                              void* d_out, int out_size, void* d_ws, size_t ws_size,
                              hipStream_t stream) {
  const float* logp    = (const float*)d_in[0];
  const int*   targets = (const int*)d_in[1];
  const int*   il      = (const int*)d_in[2];
  const int*   tl      = (const int*)d_in[3];
  float* out = (float*)d_out;

  ctc_zero_kernel<<<1, 1, 0, stream>>>(out);
  ctc_alpha_kernel<<<B, NW * 64, 0, stream>>>(logp, targets, il, tl, out);
}

// Round 6
// 414.136 us; speedup vs baseline: 2.2556x; 1.2202x over previous
//
#include <hip/hip_runtime.h>

#define LOG2E 1.4426950408889634f
#define LN2   0.6931471805599453f

namespace {
constexpr int B    = 64;
constexpr int T    = 2000;
constexpr int V    = 256;
constexpr int S    = 400;
constexpr int NW   = 7;                         // waves per chain (7*128=896 >= 801 states)
constexpr int CHK  = 8;                         // steps per handoff chunk
constexpr int NCT  = (T - 1 + CHK - 1) / CHK;   // 250 chunks available
constexpr int BSTR = 12;                        // bnd floats per chunk (16B aligned)
}

__device__ __forceinline__ float fexp2(float x){ return __builtin_amdgcn_exp2f(x); }
__device__ __forceinline__ float flog2(float x){ return __builtin_amdgcn_logf(x); }

// whole-wave shift right by 1 lane (lane i gets lane i-1's value).
__device__ __forceinline__ float wave_shr1(float x) {
  int v = __builtin_amdgcn_update_dpp(0, __builtin_bit_cast(int, x),
                                      0x138 /*WAVE_SHR1*/, 0xf, 0xf, true);
  return __builtin_bit_cast(float, v);
}

// One block (7 waves) per batch item; lane owns states {2g, 2g+1}, g = tid.
// PROBABILITY domain: a_new = (a + a_below + sk*a_below2) * p  — no
// transcendentals in the recurrence. Magnitude tracked per-lane as integer
// exponent E (real = a * 2^E), renormalized per 8-step chunk (frexp/ldexp).
// The alpha front advances exactly 1 lane/step, so zero-lanes pre-adopt a
// usable E from 8 lanes back (or the producer's E) one chunk before mass
// arrives. Cross-wave handoff: 8 boundary values + producer E per chunk via
// LDS + acquire/release counter; no s_barrier in the loop.
__global__ __launch_bounds__(NW * 64)
void ctc_alpha_kernel(const float* __restrict__ logp,
                      const int* __restrict__ targets,
                      const int* __restrict__ input_len,
                      const int* __restrict__ target_len,
                      float* __restrict__ out)
{
  const int b    = blockIdx.x;
  const int tid  = threadIdx.x;
  const int w    = tid >> 6;
  const int lane = tid & 63;
  const bool lane0 = (lane == 0);
  const float* __restrict__ lp = logp + (size_t)b * T * V;
  const int il = input_len[b];
  const int tl = target_len[b];
  const int Lb = 2 * tl + 1;

  __shared__ float bnd[NW - 1][NCT * BSTR];   // 72 KB boundary streams
  __shared__ int   cnt[NW - 1];
  __shared__ float pblk[T];                   // p_blank at time (i+1), 8 KB
  __shared__ float afin[NW * 64 * 2];         // final log2-alpha readout

  if (tid < NW - 1) cnt[tid] = 0;

  // token constants for odd state 2*tid+1
  const int* tg = targets + (size_t)b * S;
  const int k1 = (tid < S) ? tid : (S - 1);
  const int e1 = tg[k1];
  const float sk1 = (k1 == 0 || e1 != tg[k1 - 1]) ? 1.0f : 0.0f;

  // precompute blank probs: pblk[i] = exp(lp[i+1][blank])
  for (int i = tid; i < T; i += NW * 64) {
    int t = (i + 1 < T) ? (i + 1) : (T - 1);
    pblk[i] = fexp2(lp[(size_t)t * V + 1] * LOG2E);
  }
  __syncthreads();   // barrier 1

  const bool active = (w * 128) < Lb;
  if (active) {
    float a0 = 0.0f, a1 = 0.0f;
    int   E  = 0;
    if (tid == 0) {
      a0 = fexp2(lp[1]  * LOG2E);
      a1 = fexp2(lp[e1] * LOG2E);
    }

    // preload token logp chunk 0 (t = 1..8)
    float tokL[CHK];
    #pragma unroll
    for (int i = 0; i < CHK; ++i) tokL[i] = lp[(size_t)(1 + i) * V + e1];

    const int NCH = (il - 1 + CHK - 1) / CHK;
    for (int c = 0; c < NCH; ++c) {
      const int t0 = 1 + c * CHK;

      // current chunk token probs
      float tokP[CHK];
      #pragma unroll
      for (int i = 0; i < CHK; ++i) tokP[i] = fexp2(tokL[i] * LOG2E);

      // prefetch next chunk token logps
      float nl[CHK];
      const bool pf = (c + 1 < NCT);
      if (pf) {
        #pragma unroll
        for (int i = 0; i < CHK; ++i) {
          int tt = t0 + CHK + i; if (tt > T - 1) tt = T - 1;
          nl[i] = lp[(size_t)tt * V + e1];
        }
      }

      // blank probs for this chunk (broadcast LDS reads)
      float pbk[CHK];
      {
        float4 q0 = *(const float4*)&pblk[c * CHK];
        float4 q1 = *(const float4*)&pblk[c * CHK + 4];
        pbk[0]=q0.x; pbk[1]=q0.y; pbk[2]=q0.z; pbk[3]=q0.w;
        pbk[4]=q1.x; pbk[5]=q1.y; pbk[6]=q1.z; pbk[7]=q1.w;
      }

      // consume boundary chunk (values at t = c*8 .. c*8+7, scale Ep)
      float bq[CHK];
      int Ep = 0;
      if (w > 0) {
        while (__hip_atomic_load(&cnt[w - 1], __ATOMIC_ACQUIRE,
                                 __HIP_MEMORY_SCOPE_WORKGROUP) < c + 1)
          __builtin_amdgcn_s_sleep(1);
        const float* src = &bnd[w - 1][c * BSTR];
        float4 q0 = *(const float4*)(src);
        float4 q1 = *(const float4*)(src + 4);
        bq[0]=q0.x; bq[1]=q0.y; bq[2]=q0.z; bq[3]=q0.w;
        bq[4]=q1.x; bq[5]=q1.y; bq[6]=q1.z; bq[7]=q1.w;
        Ep = __float_as_int(src[8]);
      } else {
        #pragma unroll
        for (int i = 0; i < CHK; ++i) bq[i] = 0.0f;
      }

      // per-chunk exponent bookkeeping (all shuffles independent/parallel)
      const float mz  = fmaxf(a0, a1);
      const int   E1o = __shfl_up(E, 1);
      const int   E8  = __shfl_up(E, 8);
      const int   E9  = __shfl_up(E, 9);
      const float mz1 = __shfl_up(mz, 1);
      if (mz == 0.0f) E = (lane < 8) ? Ep : E8;          // pre-adopt scale
      int E1 = (mz1 == 0.0f) ? ((lane <= 8) ? Ep : E9) : E1o;
      if (lane0) E1 = (w == 0) ? E : Ep;                 // w0: f=1 (hl=0)
      int d = E1 - E; d = d > 126 ? 126 : (d < -126 ? -126 : d);
      const float f = ldexpf(1.0f, d);
      const float a1s = a1;                              // chunk-start value

      float pub[CHK];
      #pragma unroll
      for (int i = 0; i < CHK; ++i) {
        const int t = t0 + i;
        if (t < il) {                       // wave-uniform freeze predicate
          float hl = wave_shr1(a1);
          hl = lane0 ? bq[i] : hl;
          hl *= f;
          float s01 = a1 + a0;
          a1 = __builtin_fmaf(hl, sk1, s01) * tokP[i];
          a0 = (a0 + hl) * pbk[i];
        }
        pub[i] = a1;
      }

      // publish (values in this chunk's scale E), then release
      if (w < NW - 1 && lane == 63) {
        float* dst = &bnd[w][c * BSTR];
        dst[0] = a1s;
        #pragma unroll
        for (int i = 0; i < CHK - 1; ++i) dst[1 + i] = pub[i];
        dst[8] = __int_as_float(E);
        __hip_atomic_store(&cnt[w], c + 1, __ATOMIC_RELEASE,
                           __HIP_MEMORY_SCOPE_WORKGROUP);
      }

      // renormalize per lane
      {
        float m2 = fmaxf(a0, a1);
        int k = 0;
        (void)frexpf(m2, &k);               // m2==0 -> k=0
        a0 = ldexpf(a0, -k);
        a1 = ldexpf(a1, -k);
        E += k;
      }

      #pragma unroll
      for (int i = 0; i < CHK; ++i) tokL[i] = nl[i];
    }

    // log2-domain readout values
    afin[2 * tid]     = flog2(a0) + (float)E;
    afin[2 * tid + 1] = flog2(a1) + (float)E;
  }
  __syncthreads();   // barrier 2 (inactive waves parked here cheaply)

  if (tid == 0) {
    const float x = afin[2 * tl];
    const float y = afin[2 * tl - 1];
    const float m = fmaxf(x, y);
    const float ll = (m + flog2(fexp2(x - m) + fexp2(y - m))) * LN2;
    float loss = -ll;
    if (!(loss < 1e29f)) loss = 0.0f;
    atomicAdd(out, loss / ((float)tl * (float)B));
  }
}

__global__ void ctc_zero_kernel(float* __restrict__ out) { out[0] = 0.0f; }

extern "C" void kernel_launch(void* const* d_in, const int* in_sizes, int n_in,
                              void* d_out, int out_size, void* d_ws, size_t ws_size,
                              hipStream_t stream) {
  const float* logp    = (const float*)d_in[0];
  const int*   targets = (const int*)d_in[1];
  const int*   il      = (const int*)d_in[2];
  const int*   tl      = (const int*)d_in[3];
  float* out = (float*)d_out;

  ctc_zero_kernel<<<1, 1, 0, stream>>>(out);
  ctc_alpha_kernel<<<B, NW * 64, 0, stream>>>(logp, targets, il, tl, out);
}